// Round 3
// baseline (345.424 us; speedup 1.0000x reference)
//
#include <hip/hip_runtime.h>
#include <cstdint>
#include <cstddef>

#define BATCH 16384
#define FEAT  128
#define HID   1024

using bf16x8 = __attribute__((ext_vector_type(8))) __bf16;
using f32x4  = __attribute__((ext_vector_type(4))) float;

#define VMCNT(n) asm volatile("s_waitcnt vmcnt(" #n ")" ::: "memory")
#define BAR()    asm volatile("s_barrier" ::: "memory")

__device__ __forceinline__ unsigned short f2bf(float f) {
  union { float f; unsigned u; } v; v.f = f;
  unsigned r = v.u + 0x7FFFu + ((v.u >> 16) & 1u);
  return (unsigned short)(r >> 16);
}
__device__ __forceinline__ float bf2f(unsigned short b) {
  union { unsigned u; float f; } v; v.u = (unsigned)b << 16;
  return v.f;
}

__device__ __forceinline__ void async16(const unsigned short* g, unsigned short* l) {
  __builtin_amdgcn_global_load_lds(
      (const __attribute__((address_space(1))) unsigned int*)g,
      (__attribute__((address_space(3))) unsigned int*)l, 16, 0, 0);
}

// ============================================================================
// gk8: 256x256-tile pipelined GEMM (T1+T2+T3+T4+T5) for the two K=1024 GEMMs.
// 512 threads = 8 waves (2M x 4N), per-wave 128x64 output, BK=64.
// R18 DEPENDENCY FIX: in the 2Mx4N layout a wave's operand needs are fixed by
// (wave_m, wave_n), NOT by phase — M/N-half staging units gave wave_m=1 /
// wave_n>=2 unpublished reads in P1 (R16/R17 NaN). Staging units are now
// K-SPLIT: U1(t) = all A rows + all B cols @ kc=0 (32 chunks), U2(t) = kc=1.
// Every wave reads only U1 in phase-A, only U2 in phase-B -> wave-uniform
// publishes. Ledger (4 ops/unit/wave, in-order retire):
//   prologue: issue U1(0),U2(0); vmcnt(4) retires U1(0); bar.
//   tile t phase-A: read U1(t); stage U1(t+1) [outst 8]; 2x16-MFMA clusters;
//                   vmcnt(4) retires U2(t); bar (publish U2(t)).
//   tile t phase-B: read U2(t); stage U2(t+1) [outst 8]; 2x16-MFMA clusters;
//                   vmcnt(4) retires U1(t+1); bar (publish U1(t+1)).
// Never drains below 4 in the main loop; single vmcnt(0) in the peeled tail.
// Barriers are asm-with-memory-clobber so ds_reads can't hoist across.
// DUAL=1: M-stacked dual — A-chunks 0..7 from A1 rows m0.., 8..15 from A2
// rows m0.. (same m-range); wave_m=1 computes D1. EPI 2 exchanges D1 as f32
// through LDS with rotated index ml*256+((n+4*ml)&255) (<=2-way banks,
// fits the existing 128 KiB buffer).
// ============================================================================
template <int NXB, int NBY, int DUAL, int EPI>
__global__ __launch_bounds__(512, 2) void gk8(
    const unsigned short* __restrict__ A1, const unsigned short* __restrict__ A2,
    const unsigned short* __restrict__ Bt, int K,
    const float* __restrict__ bias,
    unsigned short* __restrict__ outH)
{
  __shared__ __align__(16) unsigned short lds[65536];   // 2 bufs x 32768 ushort = 128 KiB

  const int tid = threadIdx.x;
  const int wave = tid >> 6, lane = tid & 63;
  const int wave_m = wave >> 2, wave_n = wave & 3;
  const int wn0 = wave_n * 64;

  // XCD-aware block mapping (dispatch round-robin -> XCD owns contiguous M)
  const int xcd = (int)blockIdx.x & 7;
  const int l   = (int)blockIdx.x >> 3;
  const int xb  = xcd * (NXB / 8) + (l / NBY);
  const int yb  = l % NBY;
  const int m0  = xb * (DUAL ? 128 : 256);
  const int n0  = yb * 256;

  // staging-side addressing (global fetch pre-swizzled to match LDS layout)
  const int rS = lane >> 2;
  const int qS = (lane & 3) ^ ((rS >> 1) & 3);

  // Per-wave staging sources: A m_chunk {wave, wave+8}, B n_chunk {wave, wave+8}.
  // LDS chunk addr: A = kc*8192 + m_chunk*512 ; B = 16384 + kc*8192 + n_chunk*512.
  const unsigned short* spA1 = DUAL ? A2 : A1;
  const size_t soA0 = (size_t)(m0 + wave * 16 + rS) * K + qS * 8;
  const size_t soA1 = (size_t)((DUAL ? m0 : m0 + 128) + wave * 16 + rS) * K + qS * 8;
  const size_t soB0 = (size_t)(n0 + wave * 16 + rS) * K + qS * 8;
  const size_t soB1 = (size_t)(n0 + 128 + wave * 16 + rS) * K + qS * 8;
  const int ldA0 = wave * 512,          ldA1 = (wave + 8) * 512;
  const int ldB0 = 16384 + wave * 512,  ldB1 = 16384 + (wave + 8) * 512;

  auto STGU = [&](int kc, int kt, unsigned short* nb) {
    const int gc = kt * 64 + kc * 32;
    const int lb = kc * 8192;
    async16(A1   + soA0 + gc, nb + lb + ldA0);
    async16(spA1 + soA1 + gc, nb + lb + ldA1);
    async16(Bt   + soB0 + gc, nb + lb + ldB0);
    async16(Bt   + soB1 + gc, nb + lb + ldB1);
  };

  // frag-read offset within a chunk (swizzled), chunk bases per wave
  const int r2 = lane & 15, q2 = lane >> 4;
  const int ro = r2 * 32 + ((q2 ^ ((r2 >> 1) & 3)) * 8);
  const int abase = wave_m * 8 * 512;            // + kc*8192 + i*512
  const int bbase = 16384 + wave_n * 4 * 512;    // + kc*8192 + j*512

  bf16x8 aqA[4], aqB[4], bqv[4];
  f32x4 acc[8][4] = {};

  const int NT = K >> 6;

  // prologue: stage U1(0), U2(0); publish U1(0)
  STGU(0, 0, lds);
  STGU(1, 0, lds);
  VMCNT(4);
  BAR();

  for (int t = 0; t < NT - 1; ++t) {
    const unsigned short* buf = lds + (t & 1) * 32768;
    unsigned short* nb = lds + ((t + 1) & 1) * 32768;
#pragma unroll
    for (int pkc = 0; pkc < 2; ++pkc) {
      const int kb = pkc * 8192;
#pragma unroll
      for (int i = 0; i < 4; ++i) aqA[i] = *(const bf16x8*)&buf[kb + abase + i * 512 + ro];
#pragma unroll
      for (int j = 0; j < 4; ++j) bqv[j] = *(const bf16x8*)&buf[kb + bbase + j * 512 + ro];
      STGU(pkc, t + 1, nb);
      __builtin_amdgcn_s_setprio(1);
#pragma unroll
      for (int i = 0; i < 4; ++i)
#pragma unroll
        for (int j = 0; j < 4; ++j)
          acc[i][j] = __builtin_amdgcn_mfma_f32_16x16x32_bf16(aqA[i], bqv[j], acc[i][j], 0, 0, 0);
      __builtin_amdgcn_s_setprio(0);
#pragma unroll
      for (int i = 0; i < 4; ++i) aqB[i] = *(const bf16x8*)&buf[kb + abase + (4 + i) * 512 + ro];
      __builtin_amdgcn_s_setprio(1);
#pragma unroll
      for (int i = 0; i < 4; ++i)
#pragma unroll
        for (int j = 0; j < 4; ++j)
          acc[4 + i][j] = __builtin_amdgcn_mfma_f32_16x16x32_bf16(aqB[i], bqv[j], acc[4 + i][j], 0, 0, 0);
      __builtin_amdgcn_s_setprio(0);
      VMCNT(4);   // pkc=0: retires U2(t) ; pkc=1: retires U1(t+1)
      BAR();      // publish it
    }
  }

  // ---- peeled tail tile (t = NT-1): no prefetch; single vmcnt(0) drain ----
  {
    const unsigned short* buf = lds + ((NT - 1) & 1) * 32768;
#pragma unroll
    for (int pkc = 0; pkc < 2; ++pkc) {
      const int kb = pkc * 8192;
#pragma unroll
      for (int i = 0; i < 4; ++i) aqA[i] = *(const bf16x8*)&buf[kb + abase + i * 512 + ro];
#pragma unroll
      for (int j = 0; j < 4; ++j) bqv[j] = *(const bf16x8*)&buf[kb + bbase + j * 512 + ro];
      __builtin_amdgcn_s_setprio(1);
#pragma unroll
      for (int i = 0; i < 4; ++i)
#pragma unroll
        for (int j = 0; j < 4; ++j)
          acc[i][j] = __builtin_amdgcn_mfma_f32_16x16x32_bf16(aqA[i], bqv[j], acc[i][j], 0, 0, 0);
      __builtin_amdgcn_s_setprio(0);
#pragma unroll
      for (int i = 0; i < 4; ++i) aqB[i] = *(const bf16x8*)&buf[kb + abase + (4 + i) * 512 + ro];
      __builtin_amdgcn_s_setprio(1);
#pragma unroll
      for (int i = 0; i < 4; ++i)
#pragma unroll
        for (int j = 0; j < 4; ++j)
          acc[4 + i][j] = __builtin_amdgcn_mfma_f32_16x16x32_bf16(aqB[i], bqv[j], acc[4 + i][j], 0, 0, 0);
      __builtin_amdgcn_s_setprio(0);
      if (pkc == 0) { VMCNT(0); BAR(); }   // publish U2(NT-1)
    }
  }

  // ---------------- epilogue ----------------
  if constexpr (EPI == 8) {
    float bv[4];
#pragma unroll
    for (int j = 0; j < 4; ++j) bv[j] = bias[n0 + wn0 + j * 16 + (lane & 15)];
#pragma unroll
    for (int i = 0; i < 8; ++i)
#pragma unroll
      for (int j = 0; j < 4; ++j)
#pragma unroll
        for (int rr = 0; rr < 4; ++rr) {
          const int m = m0 + wave_m * 128 + i * 16 + ((lane >> 4) << 2) + rr;
          const int n = n0 + wn0 + j * 16 + (lane & 15);
          outH[(size_t)m * HID + n] = f2bf(tanhf(acc[i][j][rr] + bv[j]));
        }
  } else {  // EPI == 2 (dual stacked): wave_m=1 holds D1, pass via rotated f32 LDS
    float* hl = (float*)lds;
    __syncthreads();
    if (wave_m == 1) {
#pragma unroll
      for (int i = 0; i < 8; ++i)
#pragma unroll
        for (int j = 0; j < 4; ++j)
#pragma unroll
          for (int rr = 0; rr < 4; ++rr) {
            const int ml = i * 16 + ((lane >> 4) << 2) + rr;
            const int n  = wn0 + j * 16 + (lane & 15);
            hl[ml * 256 + ((n + 4 * ml) & 255)] = acc[i][j][rr];
          }
    }
    __syncthreads();
    if (wave_m == 0) {
      float bv[4];
#pragma unroll
      for (int j = 0; j < 4; ++j) bv[j] = bias[n0 + wn0 + j * 16 + (lane & 15)];
#pragma unroll
      for (int i = 0; i < 8; ++i)
#pragma unroll
        for (int j = 0; j < 4; ++j)
#pragma unroll
          for (int rr = 0; rr < 4; ++rr) {
            const int ml = i * 16 + ((lane >> 4) << 2) + rr;
            const int n  = wn0 + j * 16 + (lane & 15);
            const size_t idx = (size_t)(m0 + ml) * HID + (n0 + n);
            const float h = tanhf(acc[i][j][rr] + bv[j]);
            outH[idx] = f2bf(h);
            outH[idx + (size_t)BATCH * HID] = f2bf((1.f - h * h) * hl[ml * 256 + ((n + 4 * ml) & 255)]);
          }
    }
  }
}

// ============================================================================
// gk: legacy 2-phase kernel — still used for the K=128 GEMMs (G1k1, G1k2:
// pipeline can't fill at NT=2, memory-write-bound) and the N=128 G3 steps.
// Ledger: R7 split-G2 regressed; R8 128x128 DUAL = 264 regs = 1 blk/CU (bad);
// R10/11 64x128 dual + MINW=4 -> 38% occ; R12 Euler FAILED log_det, RK2 final;
// R13 eval-1 tangent = dead code -> primal-only eval-1; R14 E1 cache removed.
// R15: eval-1 single-stream GEMMs retiled to 128x128.
// R16/R17: gk8 NaN — M/N-half staging units are wave-NON-uniform deps.
// R18: gk8 staging units K-split -> wave-uniform publishes.
// ============================================================================
template <int BM, int BN, int NXB, int NBY, int DUAL, int EPI, int MINW = 1>
__global__ __launch_bounds__(256, MINW) void gk(
    const unsigned short* __restrict__ A1, const unsigned short* __restrict__ A2,
    const unsigned short* __restrict__ Bt, int K,
    const float* __restrict__ bias, const float* __restrict__ w1last, float tval,
    const unsigned short* __restrict__ epsb,
    unsigned short* __restrict__ outH,
    float* __restrict__ z0, unsigned short* __restrict__ zsb,
    float* __restrict__ ld0,
    float czs, float dt6, int finish,
    float* __restrict__ finZ, float* __restrict__ finLd)
{
  constexpr int WM = BM / 2, WN = BN / 2;
  constexpr int RT = WM / 16, CT = WN / 16;
  constexpr int ACH = BM / 16;                       // chunks per A stream
  constexpr int NCH = (DUAL ? 2 : 1) * ACH + BN / 16;
  constexpr int NCHW = (NCH + 3) / 4;                // chunk-loop trips per wave

  __shared__ __align__(16) unsigned short lds[2][NCH * 512];
  __shared__ float rsum[BM];

  const int tid = threadIdx.x;
  const int wave = tid >> 6, lane = tid & 63;
  int xb, yb;
  if constexpr (NBY > 1) {
    const int xcd = (int)blockIdx.x & 7;   // dispatch round-robin -> XCD
    const int l   = (int)blockIdx.x >> 3;  // local index within XCD
    xb = xcd * (NXB / 8) + (l / NBY);      // contiguous M-range per XCD
    yb = l % NBY;                          // sweep N-strips fastest
  } else {
    xb = ((int)blockIdx.x & 7) * (NXB / 8) + ((int)blockIdx.x >> 3);
    yb = 0;
  }
  const int m0 = xb * BM, n0 = yb * BN;
  const int wm0 = (wave >> 1) * WM, wn0 = (wave & 1) * WN;

  f32x4 acc0[RT][CT] = {};
  f32x4 acc1[DUAL ? RT : 1][DUAL ? CT : 1] = {};
  if constexpr (EPI == 3 && DUAL) { if (tid < BM) rsum[tid] = 0.f; }

  const int r = lane >> 2;
  const int q = (lane & 3) ^ ((r >> 1) & 3);
  const int gcol = q * 8;

  auto issue = [&](int k0, int b) {
    unsigned short* ldsb = &lds[b][0];
#pragma unroll
    for (int j = 0; j < NCHW; ++j) {
      const int cid = wave + 4 * j;            // wave-uniform
      if constexpr (NCH % 4 != 0) { if (cid >= NCH) continue; }
      const unsigned short* src; int row0;
      if constexpr (DUAL) {
        if (cid < ACH)            { src = A1; row0 = m0 + cid * 16; }
        else if (cid < 2 * ACH)   { src = A2; row0 = m0 + (cid - ACH) * 16; }
        else                      { src = Bt; row0 = n0 + (cid - 2 * ACH) * 16; }
      } else {
        if (cid < ACH)            { src = A1; row0 = m0 + cid * 16; }
        else                      { src = Bt; row0 = n0 + (cid - ACH) * 16; }
      }
      async16(src + (size_t)(row0 + r) * K + k0 + gcol, ldsb + cid * 512);
    }
  };

  const int r2 = lane & 15, q2 = lane >> 4;
  const int ro = r2 * 32 + ((q2 ^ ((r2 >> 1) & 3)) * 8);
  constexpr int BOFF = (DUAL ? 2 : 1) * ACH;

  issue(0, 0);
  const int NIT = K >> 5;
  for (int it = 0; it < NIT; ++it) {
    __syncthreads();
    if (it + 1 < NIT) issue((it + 1) << 5, (it + 1) & 1);
    const unsigned short* buf = &lds[it & 1][0];

    bf16x8 af1[RT], af2[DUAL ? RT : 1], bfr[CT];
#pragma unroll
    for (int i = 0; i < RT; ++i) {
      af1[i] = *(const bf16x8*)&buf[((wave >> 1) * RT + i) * 512 + ro];
      if constexpr (DUAL)
        af2[i] = *(const bf16x8*)&buf[(ACH + (wave >> 1) * RT + i) * 512 + ro];
    }
#pragma unroll
    for (int j = 0; j < CT; ++j)
      bfr[j] = *(const bf16x8*)&buf[(BOFF + (wave & 1) * CT + j) * 512 + ro];

#pragma unroll
    for (int i = 0; i < RT; ++i)
#pragma unroll
      for (int j = 0; j < CT; ++j) {
        acc0[i][j] = __builtin_amdgcn_mfma_f32_16x16x32_bf16(af1[i], bfr[j], acc0[i][j], 0, 0, 0);
        if constexpr (DUAL)
          acc1[i][j] = __builtin_amdgcn_mfma_f32_16x16x32_bf16(af2[i], bfr[j], acc1[i][j], 0, 0, 0);
      }
  }

  if constexpr (EPI == 2) {
#pragma unroll
    for (int i = 0; i < RT; ++i)
#pragma unroll
      for (int j = 0; j < CT; ++j)
#pragma unroll
        for (int rr = 0; rr < 4; ++rr) {
          const int m = m0 + wm0 + i * 16 + ((lane >> 4) << 2) + rr;
          const int n = n0 + wn0 + j * 16 + (lane & 15);
          const size_t idx = (size_t)m * HID + n;
          float a = acc0[i][j][rr] + bias[n];
          if (w1last) a += tval * w1last[n];
          const float h = tanhf(a);
          outH[idx] = f2bf(h);
          outH[idx + (size_t)BATCH * HID] = f2bf((1.f - h * h) * acc1[i][j][rr]);
        }
  } else if constexpr (EPI == 8) {
#pragma unroll
    for (int i = 0; i < RT; ++i)
#pragma unroll
      for (int j = 0; j < CT; ++j)
#pragma unroll
        for (int rr = 0; rr < 4; ++rr) {
          const int m = m0 + wm0 + i * 16 + ((lane >> 4) << 2) + rr;
          const int n = n0 + wn0 + j * 16 + (lane & 15);
          outH[(size_t)m * HID + n] = f2bf(tanhf(acc0[i][j][rr] + bias[n]));
        }
  } else {  // EPI == 3
#pragma unroll
    for (int i = 0; i < RT; ++i)
#pragma unroll
      for (int rr = 0; rr < 4; ++rr) {
        const int ml = wm0 + i * 16 + ((lane >> 4) << 2) + rr;
        const int m = m0 + ml;
        float s = 0.f;
#pragma unroll
        for (int j = 0; j < CT; ++j) {
          const int n = n0 + wn0 + j * 16 + (lane & 15);
          const size_t idx = (size_t)m * FEAT + n;
          const float dzv = acc0[i][j][rr] + bias[n];
          if constexpr (DUAL) s += acc1[i][j][rr] * bf2f(epsb[idx]);
          if (!finish) {
            zsb[idx] = f2bf(z0[idx] + czs * dzv);
          } else {
            const float v = z0[idx] + dt6 * dzv;
            z0[idx] = v;
            zsb[idx] = f2bf(v);
            if (finZ) finZ[idx] = v;
          }
        }
        if constexpr (DUAL) {
          s += __shfl_xor(s, 8);
          s += __shfl_xor(s, 4);
          s += __shfl_xor(s, 2);
          s += __shfl_xor(s, 1);
          if ((lane & 15) == 0) atomicAdd(&rsum[ml], s);
        }
      }
    if constexpr (DUAL) {
      __syncthreads();
      if (tid < BM && finish) {
        const int m = m0 + tid;
        const float lv = ld0[m] + dt6 * (-rsum[tid]);
        ld0[m] = lv;
        if (finLd) finLd[m] = lv;
      }
    }
  }
}

// Fused prologue: 3 LDS-tiled weight transposes (fp32 -> bf16, N x R layout)
// + eps/z0/zsb/ld0 init. Blocks [0,320) do transpose tiles, rest do prep.
__global__ __launch_bounds__(256) void prologue_k(
    const float* __restrict__ W1, const float* __restrict__ W2,
    const float* __restrict__ W3,
    unsigned short* __restrict__ Wb1t, unsigned short* __restrict__ Wb2t,
    unsigned short* __restrict__ Wb3t,
    const float* __restrict__ x, const float* __restrict__ eps,
    float* __restrict__ z0, unsigned short* __restrict__ zs,
    unsigned short* __restrict__ epsb, float* __restrict__ ld0)
{
  __shared__ unsigned short t[64][65];
  const int b = blockIdx.x;
  if (b < 320) {
    const float* src; unsigned short* dst; int R, N, lb;
    if (b < 32)       { src = W1; dst = Wb1t; R = FEAT; N = HID;  lb = b; }
    else if (b < 288) { src = W2; dst = Wb2t; R = HID;  N = HID;  lb = b - 32; }
    else              { src = W3; dst = Wb3t; R = HID;  N = FEAT; lb = b - 288; }
    const int nt = N >> 6;
    const int bx = lb % nt, by = lb / nt;
    const int r0 = by << 6, c0 = bx << 6;
    const int tx = threadIdx.x & 63, ty = threadIdx.x >> 6;
#pragma unroll
    for (int k = 0; k < 16; ++k) {
      const int rr = ty * 16 + k;
      t[rr][tx] = f2bf(src[(size_t)(r0 + rr) * N + c0 + tx]);
    }
    __syncthreads();
#pragma unroll
    for (int k = 0; k < 16; ++k) {
      const int rr = ty * 16 + k;
      dst[(size_t)(c0 + rr) * R + r0 + tx] = t[tx][rr];
    }
  } else {
    const int i = (b - 320) * 256 + threadIdx.x;
    if (i < BATCH * FEAT) {
      const float v = x[i];
      z0[i] = v; zs[i] = f2bf(v);
      epsb[i] = f2bf(eps[i]);
    }
    if (i < BATCH) ld0[i] = 0.f;
  }
}

extern "C" void kernel_launch(void* const* d_in, const int* in_sizes, int n_in,
                              void* d_out, int out_size, void* d_ws, size_t ws_size,
                              hipStream_t stream) {
  const float* x   = (const float*)d_in[0];
  const float* eps = (const float*)d_in[1];
  const float* W1  = (const float*)d_in[2];   // (129, 1024)
  const float* b1  = (const float*)d_in[3];
  const float* W2  = (const float*)d_in[4];   // (1024, 1024)
  const float* b2  = (const float*)d_in[5];
  const float* W3  = (const float*)d_in[6];   // (1024, 128)
  const float* b3  = (const float*)d_in[7];
  (void)in_sizes; (void)n_in; (void)out_size; (void)ws_size;

  char* p = (char*)d_ws;
  auto alloc = [&](size_t bytes) -> void* {
    void* q = (void*)p;
    p += (bytes + 255) & ~(size_t)255;
    return q;
  };
  unsigned short* Wb1t = (unsigned short*)alloc((size_t)HID * FEAT * 2);   // [1024][128]
  unsigned short* Wb2t = (unsigned short*)alloc((size_t)HID * HID * 2);    // [1024][1024]
  unsigned short* Wb3t = (unsigned short*)alloc((size_t)FEAT * HID * 2);   // [128][1024]
  unsigned short* epsb = (unsigned short*)alloc((size_t)BATCH * FEAT * 2);
  unsigned short* zsb  = (unsigned short*)alloc((size_t)BATCH * FEAT * 2);
  float* z0  = (float*)alloc((size_t)BATCH * FEAT * 4);
  float* ld0 = (float*)alloc((size_t)BATCH * 4);
  unsigned short* h1d = (unsigned short*)alloc((size_t)2 * BATCH * HID * 2);
  unsigned short* h2d = (unsigned short*)alloc((size_t)2 * BATCH * HID * 2);

  const int GB = (BATCH * FEAT + 255) / 256;
  prologue_k<<<dim3(320 + GB), dim3(256), 0, stream>>>(
      W1, W2, W3, Wb1t, Wb2t, Wb3t, x, eps, z0, zsb, epsb, ld0);

  const float dt = 1.f;
  const float* w1l = W1 + (size_t)FEAT * HID;

  // ---- Midpoint RK2, single step over [0,1] ----
  // eval 1 (k1, t=0): PRIMAL ONLY.
  gk<128, 128, 128, 8, 0, 8, 4><<<dim3(1024), dim3(256), 0, stream>>>(
      zsb, nullptr, Wb1t, FEAT, b1, nullptr, 0.f, nullptr,
      h1d, nullptr, nullptr, nullptr, 0.f, 0.f, 0, nullptr, nullptr);
  // G2k1: pipelined 256^2 single-stream. grid 64x4 = 256 = 1 blk/CU.
  gk8<64, 4, 0, 8><<<dim3(256), dim3(512), 0, stream>>>(
      h1d, nullptr, Wb2t, HID, b2, h2d);
  // G3k1: dz = h2@W3+b3; zsb = bf16(z0 + dt/2*dz).
  gk<32, 64, 512, 2, 0, 3, 4><<<dim3(1024), dim3(256), 0, stream>>>(
      h2d, nullptr, Wb3t, HID, b3, nullptr, 0.f, nullptr,
      nullptr, z0, zsb, nullptr, 0.5f * dt, 0.f, 0, nullptr, nullptr);

  // eval 2 (k2, t=1/2): full primal+tangent, finish
  // G1: dual — h1 = tanh(zs@W1 + t*w1last + b1); dh1 = (1-h1^2)*(eps@W1)
  gk<64, 128, 256, 8, 1, 2, 4><<<dim3(2048), dim3(256), 0, stream>>>(
      zsb, epsb, Wb1t, FEAT, b1, w1l, 0.5f * dt, nullptr,
      h1d, nullptr, nullptr, nullptr, 0.f, 0.f, 0, nullptr, nullptr);
  // G2k2: pipelined 256^2 M-STACKED dual: A-chunks 0-7 = h1 (primal),
  // 8-15 = dh1 (tangent); EPI 2 fuses tanh + (1-h^2)*D1 via f32 LDS
  // exchange. grid 128x4 = 512.
  gk8<128, 4, 1, 2><<<dim3(512), dim3(512), 0, stream>>>(
      h1d, h1d + (size_t)BATCH * HID, Wb2t, HID, b2, h2d);
  // G3: dual + finish — z1 = z0 + dt*dz; ld1 = dt*(-trace)
  gk<32, 128, 512, 1, 1, 3><<<dim3(512), dim3(256), 0, stream>>>(
      h2d, h2d + (size_t)BATCH * HID, Wb3t, HID, b3, nullptr, 0.f, epsb,
      nullptr, z0, zsb, ld0, 0.f, dt, 1,
      (float*)d_out, (float*)d_out + (size_t)BATCH * FEAT);
}

// Round 4
// 344.523 us; speedup vs baseline: 1.0026x; 1.0026x over previous
//
#include <hip/hip_runtime.h>
#include <cstdint>
#include <cstddef>

#define BATCH 16384
#define FEAT  128
#define HID   1024

using bf16x8 = __attribute__((ext_vector_type(8))) __bf16;
using f32x4  = __attribute__((ext_vector_type(4))) float;

#define VMCNT(n) asm volatile("s_waitcnt vmcnt(" #n ")" ::: "memory")
#define LGKM0()  asm volatile("s_waitcnt lgkmcnt(0)" ::: "memory")
#define BAR()    asm volatile("s_barrier" ::: "memory")

__device__ __forceinline__ unsigned short f2bf(float f) {
  union { float f; unsigned u; } v; v.f = f;
  unsigned r = v.u + 0x7FFFu + ((v.u >> 16) & 1u);
  return (unsigned short)(r >> 16);
}
__device__ __forceinline__ float bf2f(unsigned short b) {
  union { unsigned u; float f; } v; v.u = (unsigned)b << 16;
  return v.f;
}

__device__ __forceinline__ void async16(const unsigned short* g, unsigned short* l) {
  __builtin_amdgcn_global_load_lds(
      (const __attribute__((address_space(1))) unsigned int*)g,
      (__attribute__((address_space(3))) unsigned int*)l, 16, 0, 0);
}

// ============================================================================
// gk8 (R19): 256x256-tile GEMM in the verified m201 cadence.
// 512 threads = 8 waves (2M x 4N), per-wave 128x64 out.
// LDS = ring of FOUR 32KB half-K-tile slots (slice = K-32): slot s%4 holds
// all 16 A-chunks + 16 B-chunks of K-slice s. Per wave per slice: stage 4
// chunks (A:wave, A:wave+8, B:wave, B:wave+8), read 12 b128, 32 MFMA.
// Slice body (m201 template): {12 ds_read ; stage slot s+3 ; VMCNT(8)
// retires slot s+1 (in-order, 4 ops/slot/wave) ; BAR publish ; LGKM0 ;
// setprio(1) 32 MFMA setprio(0) ; BAR}.
// Prefetch depth = 2.2 slices (~4400 clk) >> HBM latency (~900) — fixes
// R18's 1-phase-deep vmcnt(4) stall (112us @ 25% MfmaUtil).
// Overwrite hazard (slot s+3 == slot s-1 mod 4): closed by the post-MFMA
// barrier — reads are lgkm-complete before own MFMA < closing BAR < any
// wave's overwrite issue. Publish hazard: vmcnt retires own 4 oldest
// (= slot s+1), BAR makes it block-wide. Tail peel: VMCNT(4), VMCNT(0).
// R16/R17 lesson: staging-unit deps must be wave-UNIFORM (K-split slices,
// every wave reads every slot) — preserved here.
// DUAL=1: M-stacked dual — A-chunks 0..7 = A1 rows m0.., 8..15 = A2 rows
// m0.. (same m-range); wave_m=1 computes D1; EPI 2 exchanges D1 as f32 via
// rotated-index LDS overlay (<=2-way banks, fits 128KiB).
// ============================================================================
template <int NXB, int NBY, int DUAL, int EPI>
__global__ __launch_bounds__(512, 2) void gk8(
    const unsigned short* __restrict__ A1, const unsigned short* __restrict__ A2,
    const unsigned short* __restrict__ Bt, int K,
    const float* __restrict__ bias,
    unsigned short* __restrict__ outH)
{
  __shared__ __align__(16) unsigned short lds[65536];   // 4 slots x 16384 ushort = 128 KiB

  const int tid = threadIdx.x;
  const int wave = tid >> 6, lane = tid & 63;
  const int wave_m = wave >> 2, wave_n = wave & 3;
  const int wn0 = wave_n * 64;

  // XCD-aware block mapping (dispatch round-robin -> XCD owns contiguous M)
  const int xcd = (int)blockIdx.x & 7;
  const int l   = (int)blockIdx.x >> 3;
  const int xb  = xcd * (NXB / 8) + (l / NBY);
  const int yb  = l % NBY;
  const int m0  = xb * (DUAL ? 128 : 256);
  const int n0  = yb * 256;

  // staging-side addressing (global fetch pre-swizzled to match LDS layout)
  const int rS = lane >> 2;
  const int qS = (lane & 3) ^ ((rS >> 1) & 3);

  // Per-wave staging: A m-chunk {wave, wave+8}, B n-chunk {wave, wave+8}.
  // Slot layout (16384 ushort): A chunks 0..15 at c*512, B chunks at 8192+c*512.
  const unsigned short* spA1 = DUAL ? A2 : A1;
  const size_t soA0 = (size_t)(m0 + wave * 16 + rS) * K + qS * 8;
  const size_t soA1 = (size_t)((DUAL ? m0 : m0 + 128) + wave * 16 + rS) * K + qS * 8;
  const size_t soB0 = (size_t)(n0 + wave * 16 + rS) * K + qS * 8;
  const size_t soB1 = (size_t)(n0 + 128 + wave * 16 + rS) * K + qS * 8;
  const int ldA0 = wave * 512,         ldA1 = (wave + 8) * 512;
  const int ldB0 = 8192 + wave * 512,  ldB1 = 8192 + (wave + 8) * 512;

  auto STGU = [&](int s) {   // stage all 4 of this wave's chunks for K-slice s
    unsigned short* nb = lds + (s & 3) * 16384;
    const int gc = s * 32;
    async16(A1   + soA0 + gc, nb + ldA0);
    async16(spA1 + soA1 + gc, nb + ldA1);
    async16(Bt   + soB0 + gc, nb + ldB0);
    async16(Bt   + soB1 + gc, nb + ldB1);
  };

  // frag-read offset within a chunk (swizzled), chunk bases per wave
  const int r2 = lane & 15, q2 = lane >> 4;
  const int ro = r2 * 32 + ((q2 ^ ((r2 >> 1) & 3)) * 8);
  const int abase = wave_m * 8 * 512;          // A chunks wave_m*8 + i
  const int bbase = 8192 + wave_n * 4 * 512;   // B chunks wave_n*4 + j

  bf16x8 aq[8], bq[4];
  f32x4 acc[8][4] = {};

  const int NS = K >> 5;   // K-32 slices

#define GK8_SLICE(s_, WAITER, DO_STAGE)                                        \
  {                                                                            \
    const unsigned short* buf = lds + ((s_) & 3) * 16384;                      \
    _Pragma("unroll")                                                          \
    for (int i = 0; i < 8; ++i) aq[i] = *(const bf16x8*)&buf[abase + i * 512 + ro]; \
    _Pragma("unroll")                                                          \
    for (int j = 0; j < 4; ++j) bq[j] = *(const bf16x8*)&buf[bbase + j * 512 + ro]; \
    if (DO_STAGE) STGU((s_) + 3);                                              \
    WAITER;                                                                    \
    BAR();                                                                     \
    LGKM0();                                                                   \
    __builtin_amdgcn_s_setprio(1);                                             \
    _Pragma("unroll")                                                          \
    for (int i = 0; i < 8; ++i)                                                \
      _Pragma("unroll")                                                        \
      for (int j = 0; j < 4; ++j)                                              \
        acc[i][j] = __builtin_amdgcn_mfma_f32_16x16x32_bf16(aq[i], bq[j], acc[i][j], 0, 0, 0); \
    __builtin_amdgcn_s_setprio(0);                                             \
    BAR();                                                                     \
  }

  // prologue: stage slots 0..2 (12 ops/wave); retire slot 0; publish.
  STGU(0); STGU(1); STGU(2);
  VMCNT(8);
  BAR();

  for (int s = 0; s < NS - 3; ++s)
    GK8_SLICE(s, VMCNT(8), true);     // retires slot s+1; stages slot s+3

  GK8_SLICE(NS - 3, VMCNT(4), false); // retires slot NS-2
  GK8_SLICE(NS - 2, VMCNT(0), false); // retires slot NS-1

  {  // last slice: slot published, nothing outstanding — no barriers needed
    const unsigned short* buf = lds + ((NS - 1) & 3) * 16384;
#pragma unroll
    for (int i = 0; i < 8; ++i) aq[i] = *(const bf16x8*)&buf[abase + i * 512 + ro];
#pragma unroll
    for (int j = 0; j < 4; ++j) bq[j] = *(const bf16x8*)&buf[bbase + j * 512 + ro];
    LGKM0();
    __builtin_amdgcn_s_setprio(1);
#pragma unroll
    for (int i = 0; i < 8; ++i)
#pragma unroll
      for (int j = 0; j < 4; ++j)
        acc[i][j] = __builtin_amdgcn_mfma_f32_16x16x32_bf16(aq[i], bq[j], acc[i][j], 0, 0, 0);
    __builtin_amdgcn_s_setprio(0);
  }
#undef GK8_SLICE

  // ---------------- epilogue ----------------
  if constexpr (EPI == 8) {
    float bv[4];
#pragma unroll
    for (int j = 0; j < 4; ++j) bv[j] = bias[n0 + wn0 + j * 16 + (lane & 15)];
#pragma unroll
    for (int i = 0; i < 8; ++i)
#pragma unroll
      for (int j = 0; j < 4; ++j)
#pragma unroll
        for (int rr = 0; rr < 4; ++rr) {
          const int m = m0 + wave_m * 128 + i * 16 + ((lane >> 4) << 2) + rr;
          const int n = n0 + wn0 + j * 16 + (lane & 15);
          outH[(size_t)m * HID + n] = f2bf(tanhf(acc[i][j][rr] + bv[j]));
        }
  } else {  // EPI == 2 (dual stacked): wave_m=1 holds D1, pass via rotated f32 LDS
    float* hl = (float*)lds;
    __syncthreads();
    if (wave_m == 1) {
#pragma unroll
      for (int i = 0; i < 8; ++i)
#pragma unroll
        for (int j = 0; j < 4; ++j)
#pragma unroll
          for (int rr = 0; rr < 4; ++rr) {
            const int ml = i * 16 + ((lane >> 4) << 2) + rr;
            const int n  = wn0 + j * 16 + (lane & 15);
            hl[ml * 256 + ((n + 4 * ml) & 255)] = acc[i][j][rr];
          }
    }
    __syncthreads();
    if (wave_m == 0) {
      float bv[4];
#pragma unroll
      for (int j = 0; j < 4; ++j) bv[j] = bias[n0 + wn0 + j * 16 + (lane & 15)];
#pragma unroll
      for (int i = 0; i < 8; ++i)
#pragma unroll
        for (int j = 0; j < 4; ++j)
#pragma unroll
          for (int rr = 0; rr < 4; ++rr) {
            const int ml = i * 16 + ((lane >> 4) << 2) + rr;
            const int n  = wn0 + j * 16 + (lane & 15);
            const size_t idx = (size_t)(m0 + ml) * HID + (n0 + n);
            const float h = tanhf(acc[i][j][rr] + bv[j]);
            outH[idx] = f2bf(h);
            outH[idx + (size_t)BATCH * HID] = f2bf((1.f - h * h) * hl[ml * 256 + ((n + 4 * ml) & 255)]);
          }
    }
  }
}

// ============================================================================
// gk: legacy 2-phase kernel — still used for the K=128 GEMMs (G1k1, G1k2:
// pipeline can't fill at NT=2, memory-write-bound) and the N=128 G3 steps.
// Ledger: R7 split-G2 regressed; R8 128x128 DUAL = 264 regs = 1 blk/CU (bad);
// R10/11 64x128 dual + MINW=4 -> 38% occ; R12 Euler FAILED log_det, RK2 final;
// R13 eval-1 tangent = dead code -> primal-only eval-1; R14 E1 cache removed.
// R15: eval-1 single-stream GEMMs retiled to 128x128.
// R16/R17: gk8 NaN — M/N-half staging units are wave-NON-uniform deps.
// R18: K-split units passed but 112us @25% Mfma (1-phase prefetch too
//      shallow; reads not overlapped through barriers).
// R19: exact m201 cadence, ring-of-4 slots, depth-2.2 prefetch.
// ============================================================================
template <int BM, int BN, int NXB, int NBY, int DUAL, int EPI, int MINW = 1>
__global__ __launch_bounds__(256, MINW) void gk(
    const unsigned short* __restrict__ A1, const unsigned short* __restrict__ A2,
    const unsigned short* __restrict__ Bt, int K,
    const float* __restrict__ bias, const float* __restrict__ w1last, float tval,
    const unsigned short* __restrict__ epsb,
    unsigned short* __restrict__ outH,
    float* __restrict__ z0, unsigned short* __restrict__ zsb,
    float* __restrict__ ld0,
    float czs, float dt6, int finish,
    float* __restrict__ finZ, float* __restrict__ finLd)
{
  constexpr int WM = BM / 2, WN = BN / 2;
  constexpr int RT = WM / 16, CT = WN / 16;
  constexpr int ACH = BM / 16;                       // chunks per A stream
  constexpr int NCH = (DUAL ? 2 : 1) * ACH + BN / 16;
  constexpr int NCHW = (NCH + 3) / 4;                // chunk-loop trips per wave

  __shared__ __align__(16) unsigned short lds[2][NCH * 512];
  __shared__ float rsum[BM];

  const int tid = threadIdx.x;
  const int wave = tid >> 6, lane = tid & 63;
  int xb, yb;
  if constexpr (NBY > 1) {
    const int xcd = (int)blockIdx.x & 7;   // dispatch round-robin -> XCD
    const int l   = (int)blockIdx.x >> 3;  // local index within XCD
    xb = xcd * (NXB / 8) + (l / NBY);      // contiguous M-range per XCD
    yb = l % NBY;                          // sweep N-strips fastest
  } else {
    xb = ((int)blockIdx.x & 7) * (NXB / 8) + ((int)blockIdx.x >> 3);
    yb = 0;
  }
  const int m0 = xb * BM, n0 = yb * BN;
  const int wm0 = (wave >> 1) * WM, wn0 = (wave & 1) * WN;

  f32x4 acc0[RT][CT] = {};
  f32x4 acc1[DUAL ? RT : 1][DUAL ? CT : 1] = {};
  if constexpr (EPI == 3 && DUAL) { if (tid < BM) rsum[tid] = 0.f; }

  const int r = lane >> 2;
  const int q = (lane & 3) ^ ((r >> 1) & 3);
  const int gcol = q * 8;

  auto issue = [&](int k0, int b) {
    unsigned short* ldsb = &lds[b][0];
#pragma unroll
    for (int j = 0; j < NCHW; ++j) {
      const int cid = wave + 4 * j;            // wave-uniform
      if constexpr (NCH % 4 != 0) { if (cid >= NCH) continue; }
      const unsigned short* src; int row0;
      if constexpr (DUAL) {
        if (cid < ACH)            { src = A1; row0 = m0 + cid * 16; }
        else if (cid < 2 * ACH)   { src = A2; row0 = m0 + (cid - ACH) * 16; }
        else                      { src = Bt; row0 = n0 + (cid - 2 * ACH) * 16; }
      } else {
        if (cid < ACH)            { src = A1; row0 = m0 + cid * 16; }
        else                      { src = Bt; row0 = n0 + (cid - ACH) * 16; }
      }
      async16(src + (size_t)(row0 + r) * K + k0 + gcol, ldsb + cid * 512);
    }
  };

  const int r2 = lane & 15, q2 = lane >> 4;
  const int ro = r2 * 32 + ((q2 ^ ((r2 >> 1) & 3)) * 8);
  constexpr int BOFF = (DUAL ? 2 : 1) * ACH;

  issue(0, 0);
  const int NIT = K >> 5;
  for (int it = 0; it < NIT; ++it) {
    __syncthreads();
    if (it + 1 < NIT) issue((it + 1) << 5, (it + 1) & 1);
    const unsigned short* buf = &lds[it & 1][0];

    bf16x8 af1[RT], af2[DUAL ? RT : 1], bfr[CT];
#pragma unroll
    for (int i = 0; i < RT; ++i) {
      af1[i] = *(const bf16x8*)&buf[((wave >> 1) * RT + i) * 512 + ro];
      if constexpr (DUAL)
        af2[i] = *(const bf16x8*)&buf[(ACH + (wave >> 1) * RT + i) * 512 + ro];
    }
#pragma unroll
    for (int j = 0; j < CT; ++j)
      bfr[j] = *(const bf16x8*)&buf[(BOFF + (wave & 1) * CT + j) * 512 + ro];

#pragma unroll
    for (int i = 0; i < RT; ++i)
#pragma unroll
      for (int j = 0; j < CT; ++j) {
        acc0[i][j] = __builtin_amdgcn_mfma_f32_16x16x32_bf16(af1[i], bfr[j], acc0[i][j], 0, 0, 0);
        if constexpr (DUAL)
          acc1[i][j] = __builtin_amdgcn_mfma_f32_16x16x32_bf16(af2[i], bfr[j], acc1[i][j], 0, 0, 0);
      }
  }

  if constexpr (EPI == 2) {
#pragma unroll
    for (int i = 0; i < RT; ++i)
#pragma unroll
      for (int j = 0; j < CT; ++j)
#pragma unroll
        for (int rr = 0; rr < 4; ++rr) {
          const int m = m0 + wm0 + i * 16 + ((lane >> 4) << 2) + rr;
          const int n = n0 + wn0 + j * 16 + (lane & 15);
          const size_t idx = (size_t)m * HID + n;
          float a = acc0[i][j][rr] + bias[n];
          if (w1last) a += tval * w1last[n];
          const float h = tanhf(a);
          outH[idx] = f2bf(h);
          outH[idx + (size_t)BATCH * HID] = f2bf((1.f - h * h) * acc1[i][j][rr]);
        }
  } else if constexpr (EPI == 8) {
#pragma unroll
    for (int i = 0; i < RT; ++i)
#pragma unroll
      for (int j = 0; j < CT; ++j)
#pragma unroll
        for (int rr = 0; rr < 4; ++rr) {
          const int m = m0 + wm0 + i * 16 + ((lane >> 4) << 2) + rr;
          const int n = n0 + wn0 + j * 16 + (lane & 15);
          outH[(size_t)m * HID + n] = f2bf(tanhf(acc0[i][j][rr] + bias[n]));
        }
  } else {  // EPI == 3
#pragma unroll
    for (int i = 0; i < RT; ++i)
#pragma unroll
      for (int rr = 0; rr < 4; ++rr) {
        const int ml = wm0 + i * 16 + ((lane >> 4) << 2) + rr;
        const int m = m0 + ml;
        float s = 0.f;
#pragma unroll
        for (int j = 0; j < CT; ++j) {
          const int n = n0 + wn0 + j * 16 + (lane & 15);
          const size_t idx = (size_t)m * FEAT + n;
          const float dzv = acc0[i][j][rr] + bias[n];
          if constexpr (DUAL) s += acc1[i][j][rr] * bf2f(epsb[idx]);
          if (!finish) {
            zsb[idx] = f2bf(z0[idx] + czs * dzv);
          } else {
            const float v = z0[idx] + dt6 * dzv;
            z0[idx] = v;
            zsb[idx] = f2bf(v);
            if (finZ) finZ[idx] = v;
          }
        }
        if constexpr (DUAL) {
          s += __shfl_xor(s, 8);
          s += __shfl_xor(s, 4);
          s += __shfl_xor(s, 2);
          s += __shfl_xor(s, 1);
          if ((lane & 15) == 0) atomicAdd(&rsum[ml], s);
        }
      }
    if constexpr (DUAL) {
      __syncthreads();
      if (tid < BM && finish) {
        const int m = m0 + tid;
        const float lv = ld0[m] + dt6 * (-rsum[tid]);
        ld0[m] = lv;
        if (finLd) finLd[m] = lv;
      }
    }
  }
}

// Fused prologue: 3 LDS-tiled weight transposes (fp32 -> bf16, N x R layout)
// + eps/z0/zsb/ld0 init. Blocks [0,320) do transpose tiles, rest do prep.
__global__ __launch_bounds__(256) void prologue_k(
    const float* __restrict__ W1, const float* __restrict__ W2,
    const float* __restrict__ W3,
    unsigned short* __restrict__ Wb1t, unsigned short* __restrict__ Wb2t,
    unsigned short* __restrict__ Wb3t,
    const float* __restrict__ x, const float* __restrict__ eps,
    float* __restrict__ z0, unsigned short* __restrict__ zs,
    unsigned short* __restrict__ epsb, float* __restrict__ ld0)
{
  __shared__ unsigned short t[64][65];
  const int b = blockIdx.x;
  if (b < 320) {
    const float* src; unsigned short* dst; int R, N, lb;
    if (b < 32)       { src = W1; dst = Wb1t; R = FEAT; N = HID;  lb = b; }
    else if (b < 288) { src = W2; dst = Wb2t; R = HID;  N = HID;  lb = b - 32; }
    else              { src = W3; dst = Wb3t; R = HID;  N = FEAT; lb = b - 288; }
    const int nt = N >> 6;
    const int bx = lb % nt, by = lb / nt;
    const int r0 = by << 6, c0 = bx << 6;
    const int tx = threadIdx.x & 63, ty = threadIdx.x >> 6;
#pragma unroll
    for (int k = 0; k < 16; ++k) {
      const int rr = ty * 16 + k;
      t[rr][tx] = f2bf(src[(size_t)(r0 + rr) * N + c0 + tx]);
    }
    __syncthreads();
#pragma unroll
    for (int k = 0; k < 16; ++k) {
      const int rr = ty * 16 + k;
      dst[(size_t)(c0 + rr) * R + r0 + tx] = t[tx][rr];
    }
  } else {
    const int i = (b - 320) * 256 + threadIdx.x;
    if (i < BATCH * FEAT) {
      const float v = x[i];
      z0[i] = v; zs[i] = f2bf(v);
      epsb[i] = f2bf(eps[i]);
    }
    if (i < BATCH) ld0[i] = 0.f;
  }
}

extern "C" void kernel_launch(void* const* d_in, const int* in_sizes, int n_in,
                              void* d_out, int out_size, void* d_ws, size_t ws_size,
                              hipStream_t stream) {
  const float* x   = (const float*)d_in[0];
  const float* eps = (const float*)d_in[1];
  const float* W1  = (const float*)d_in[2];   // (129, 1024)
  const float* b1  = (const float*)d_in[3];
  const float* W2  = (const float*)d_in[4];   // (1024, 1024)
  const float* b2  = (const float*)d_in[5];
  const float* W3  = (const float*)d_in[6];   // (1024, 128)
  const float* b3  = (const float*)d_in[7];
  (void)in_sizes; (void)n_in; (void)out_size; (void)ws_size;

  char* p = (char*)d_ws;
  auto alloc = [&](size_t bytes) -> void* {
    void* q = (void*)p;
    p += (bytes + 255) & ~(size_t)255;
    return q;
  };
  unsigned short* Wb1t = (unsigned short*)alloc((size_t)HID * FEAT * 2);   // [1024][128]
  unsigned short* Wb2t = (unsigned short*)alloc((size_t)HID * HID * 2);    // [1024][1024]
  unsigned short* Wb3t = (unsigned short*)alloc((size_t)FEAT * HID * 2);   // [128][1024]
  unsigned short* epsb = (unsigned short*)alloc((size_t)BATCH * FEAT * 2);
  unsigned short* zsb  = (unsigned short*)alloc((size_t)BATCH * FEAT * 2);
  float* z0  = (float*)alloc((size_t)BATCH * FEAT * 4);
  float* ld0 = (float*)alloc((size_t)BATCH * 4);
  unsigned short* h1d = (unsigned short*)alloc((size_t)2 * BATCH * HID * 2);
  unsigned short* h2d = (unsigned short*)alloc((size_t)2 * BATCH * HID * 2);

  const int GB = (BATCH * FEAT + 255) / 256;
  prologue_k<<<dim3(320 + GB), dim3(256), 0, stream>>>(
      W1, W2, W3, Wb1t, Wb2t, Wb3t, x, eps, z0, zsb, epsb, ld0);

  const float dt = 1.f;
  const float* w1l = W1 + (size_t)FEAT * HID;

  // ---- Midpoint RK2, single step over [0,1] ----
  // eval 1 (k1, t=0): PRIMAL ONLY.
  gk<128, 128, 128, 8, 0, 8, 4><<<dim3(1024), dim3(256), 0, stream>>>(
      zsb, nullptr, Wb1t, FEAT, b1, nullptr, 0.f, nullptr,
      h1d, nullptr, nullptr, nullptr, 0.f, 0.f, 0, nullptr, nullptr);
  // G2k1: pipelined 256^2 single-stream. grid 64x4 = 256 = 1 blk/CU.
  gk8<64, 4, 0, 8><<<dim3(256), dim3(512), 0, stream>>>(
      h1d, nullptr, Wb2t, HID, b2, h2d);
  // G3k1: dz = h2@W3+b3; zsb = bf16(z0 + dt/2*dz).
  gk<32, 64, 512, 2, 0, 3, 4><<<dim3(1024), dim3(256), 0, stream>>>(
      h2d, nullptr, Wb3t, HID, b3, nullptr, 0.f, nullptr,
      nullptr, z0, zsb, nullptr, 0.5f * dt, 0.f, 0, nullptr, nullptr);

  // eval 2 (k2, t=1/2): full primal+tangent, finish
  // G1: dual — h1 = tanh(zs@W1 + t*w1last + b1); dh1 = (1-h1^2)*(eps@W1)
  gk<64, 128, 256, 8, 1, 2, 4><<<dim3(2048), dim3(256), 0, stream>>>(
      zsb, epsb, Wb1t, FEAT, b1, w1l, 0.5f * dt, nullptr,
      h1d, nullptr, nullptr, nullptr, 0.f, 0.f, 0, nullptr, nullptr);
  // G2k2: pipelined 256^2 M-STACKED dual: A-chunks 0-7 = h1 (primal),
  // 8-15 = dh1 (tangent); EPI 2 fuses tanh + (1-h^2)*D1 via f32 LDS
  // exchange. grid 128x4 = 512.
  gk8<128, 4, 1, 2><<<dim3(512), dim3(512), 0, stream>>>(
      h1d, h1d + (size_t)BATCH * HID, Wb2t, HID, b2, h2d);
  // G3: dual + finish — z1 = z0 + dt*dz; ld1 = dt*(-trace)
  gk<32, 128, 512, 1, 1, 3><<<dim3(512), dim3(256), 0, stream>>>(
      h2d, h2d + (size_t)BATCH * HID, Wb3t, HID, b3, nullptr, 0.f, epsb,
      nullptr, z0, zsb, ld0, 0.f, dt, 1,
      (float*)d_out, (float*)d_out + (size_t)BATCH * FEAT);
}

// Round 5
// 326.976 us; speedup vs baseline: 1.0564x; 1.0537x over previous
//
#include <hip/hip_runtime.h>
#include <cstdint>
#include <cstddef>

#define BATCH 16384
#define FEAT  128
#define HID   1024

using bf16x8 = __attribute__((ext_vector_type(8))) __bf16;
using f32x4  = __attribute__((ext_vector_type(4))) float;

#define VMCNT(n) asm volatile("s_waitcnt vmcnt(" #n ")" ::: "memory")
#define BAR()    asm volatile("s_barrier" ::: "memory")

template <int N> __device__ __forceinline__ void vmcnt_c() {
  if constexpr (N == 0) VMCNT(0);
  else if constexpr (N == 3) VMCNT(3);
  else if constexpr (N == 4) VMCNT(4);
  else if constexpr (N == 8) VMCNT(8);
}

__device__ __forceinline__ unsigned short f2bf(float f) {
  union { float f; unsigned u; } v; v.f = f;
  unsigned r = v.u + 0x7FFFu + ((v.u >> 16) & 1u);
  return (unsigned short)(r >> 16);
}
__device__ __forceinline__ float bf2f(unsigned short b) {
  union { unsigned u; float f; } v; v.u = (unsigned)b << 16;
  return v.f;
}

__device__ __forceinline__ void async16(const unsigned short* g, unsigned short* l) {
  __builtin_amdgcn_global_load_lds(
      (const __attribute__((address_space(1))) unsigned int*)g,
      (__attribute__((address_space(3))) unsigned int*)l, 16, 0, 0);
}

// ============================================================================
// gk: the proven 2-phase kernel, now with counted-vmcnt staging pipeline.
// R20: when each wave stages a uniform OPB = NCH/4 chunks per buffer
// (NCH%4==0), use THREE LDS buffers + depth-2 prefetch and replace
// __syncthreads() (which drains vmcnt(0): loads issued only ~1 compute
// phase (<900clk HBM latency) earlier -> per-iteration stall) with
// {VMCNT(OPB); s_barrier}: retires buf(it) issued TWO phases ago, leaves
// buf(it+1) in flight. Publish unit = whole buffer staged by all waves
// (wave-uniform — R16/R17 lesson). Overwrite of phys buf (it+2)%3 is
// ordered by the top-of-loop barrier (reads(it-1) lgkm-complete before
// each wave's MFMA(it-1) which precedes its barrier arrival).
// Tail: VMCNT(OPB) -> VMCNT(0). NCH%4!=0 kernels (G3k1) keep legacy path.
// Ledger: R7 split-G2 regressed; R8 128x128 DUAL 1 blk/CU bad; R10/11
// 64x128 dual MINW=4 -> 38% occ; R12 Euler FAILED, RK2 final; R13 eval-1
// primal-only; R15 eval-1 retiled 128x128 (R0 = 309.8us).
// R16-R19: 8-phase gk8 arc — R16/R17 NaN (wave-non-uniform publishes),
// R18 112us@25%, R19 m201-cadence 117us@24% — both WORSE than 2-phase gk
// (96us@31%); 8-phase does not transfer to this geometry. Abandoned.
// ============================================================================
template <int BM, int BN, int NXB, int NBY, int DUAL, int EPI, int MINW = 1>
__global__ __launch_bounds__(256, MINW) void gk(
    const unsigned short* __restrict__ A1, const unsigned short* __restrict__ A2,
    const unsigned short* __restrict__ Bt, int K,
    const float* __restrict__ bias, const float* __restrict__ w1last, float tval,
    const unsigned short* __restrict__ epsb,
    unsigned short* __restrict__ outH,
    float* __restrict__ z0, unsigned short* __restrict__ zsb,
    float* __restrict__ ld0,
    float czs, float dt6, int finish,
    float* __restrict__ finZ, float* __restrict__ finLd)
{
  constexpr int WM = BM / 2, WN = BN / 2;
  constexpr int RT = WM / 16, CT = WN / 16;
  constexpr int ACH = BM / 16;                       // chunks per A stream
  constexpr int NCH = (DUAL ? 2 : 1) * ACH + BN / 16;
  constexpr int NCHW = (NCH + 3) / 4;                // chunk-loop trips per wave
  constexpr bool PIPE = (NCH % 4 == 0);              // uniform ops/buf per wave
  constexpr int OPB = NCH / 4;                       // staging ops per buf per wave
  constexpr int NBUF = PIPE ? 3 : 2;

  __shared__ __align__(16) unsigned short lds[NBUF][NCH * 512];
  __shared__ float rsum[BM];

  const int tid = threadIdx.x;
  const int wave = tid >> 6, lane = tid & 63;
  int xb, yb;
  if constexpr (NBY > 1) {
    const int xcd = (int)blockIdx.x & 7;   // dispatch round-robin -> XCD
    const int l   = (int)blockIdx.x >> 3;  // local index within XCD
    xb = xcd * (NXB / 8) + (l / NBY);      // contiguous M-range per XCD
    yb = l % NBY;                          // sweep N-strips fastest
  } else {
    xb = ((int)blockIdx.x & 7) * (NXB / 8) + ((int)blockIdx.x >> 3);
    yb = 0;
  }
  const int m0 = xb * BM, n0 = yb * BN;
  const int wm0 = (wave >> 1) * WM, wn0 = (wave & 1) * WN;

  f32x4 acc0[RT][CT] = {};
  f32x4 acc1[DUAL ? RT : 1][DUAL ? CT : 1] = {};
  if constexpr (EPI == 3 && DUAL) { if (tid < BM) rsum[tid] = 0.f; }

  const int r = lane >> 2;
  const int q = (lane & 3) ^ ((r >> 1) & 3);
  const int gcol = q * 8;

  auto issue = [&](int k0, int b) {
    unsigned short* ldsb = &lds[b][0];
#pragma unroll
    for (int j = 0; j < NCHW; ++j) {
      const int cid = wave + 4 * j;            // wave-uniform
      if constexpr (NCH % 4 != 0) { if (cid >= NCH) continue; }
      const unsigned short* src; int row0;
      if constexpr (DUAL) {
        if (cid < ACH)            { src = A1; row0 = m0 + cid * 16; }
        else if (cid < 2 * ACH)   { src = A2; row0 = m0 + (cid - ACH) * 16; }
        else                      { src = Bt; row0 = n0 + (cid - 2 * ACH) * 16; }
      } else {
        if (cid < ACH)            { src = A1; row0 = m0 + cid * 16; }
        else                      { src = Bt; row0 = n0 + (cid - ACH) * 16; }
      }
      async16(src + (size_t)(row0 + r) * K + k0 + gcol, ldsb + cid * 512);
    }
  };

  const int r2 = lane & 15, q2 = lane >> 4;
  const int ro = r2 * 32 + ((q2 ^ ((r2 >> 1) & 3)) * 8);
  constexpr int BOFF = (DUAL ? 2 : 1) * ACH;

  const int NIT = K >> 5;

  auto compute_it = [&](const unsigned short* buf) {
    bf16x8 af1[RT], af2[DUAL ? RT : 1], bfr[CT];
#pragma unroll
    for (int i = 0; i < RT; ++i) {
      af1[i] = *(const bf16x8*)&buf[((wave >> 1) * RT + i) * 512 + ro];
      if constexpr (DUAL)
        af2[i] = *(const bf16x8*)&buf[(ACH + (wave >> 1) * RT + i) * 512 + ro];
    }
#pragma unroll
    for (int j = 0; j < CT; ++j)
      bfr[j] = *(const bf16x8*)&buf[(BOFF + (wave & 1) * CT + j) * 512 + ro];

#pragma unroll
    for (int i = 0; i < RT; ++i)
#pragma unroll
      for (int j = 0; j < CT; ++j) {
        acc0[i][j] = __builtin_amdgcn_mfma_f32_16x16x32_bf16(af1[i], bfr[j], acc0[i][j], 0, 0, 0);
        if constexpr (DUAL)
          acc1[i][j] = __builtin_amdgcn_mfma_f32_16x16x32_bf16(af2[i], bfr[j], acc1[i][j], 0, 0, 0);
      }
  };

  if constexpr (PIPE) {
    // counted-vmcnt 3-buffer pipeline (depth 2)
    issue(0, 0);
    issue(32, 1);                       // NIT >= 2 for all users (K >= 64)
    for (int it = 0; it < NIT; ++it) {
      if (it + 1 < NIT) vmcnt_c<OPB>(); // retire buf(it), leave buf(it+1)
      else              vmcnt_c<0>();
      BAR();                            // publish buf(it) block-wide
      if (it + 2 < NIT) issue((it + 2) << 5, (it + 2) % 3);
      compute_it(&lds[it % 3][0]);
    }
  } else {
    // legacy 2-buffer __syncthreads path (non-uniform staging counts)
    issue(0, 0);
    for (int it = 0; it < NIT; ++it) {
      __syncthreads();
      if (it + 1 < NIT) issue((it + 1) << 5, (it + 1) & 1);
      compute_it(&lds[it & 1][0]);
    }
  }

  if constexpr (EPI == 2) {
#pragma unroll
    for (int i = 0; i < RT; ++i)
#pragma unroll
      for (int j = 0; j < CT; ++j)
#pragma unroll
        for (int rr = 0; rr < 4; ++rr) {
          const int m = m0 + wm0 + i * 16 + ((lane >> 4) << 2) + rr;
          const int n = n0 + wn0 + j * 16 + (lane & 15);
          const size_t idx = (size_t)m * HID + n;
          float a = acc0[i][j][rr] + bias[n];
          if (w1last) a += tval * w1last[n];
          const float h = tanhf(a);
          outH[idx] = f2bf(h);
          outH[idx + (size_t)BATCH * HID] = f2bf((1.f - h * h) * acc1[i][j][rr]);
        }
  } else if constexpr (EPI == 8) {
#pragma unroll
    for (int i = 0; i < RT; ++i)
#pragma unroll
      for (int j = 0; j < CT; ++j)
#pragma unroll
        for (int rr = 0; rr < 4; ++rr) {
          const int m = m0 + wm0 + i * 16 + ((lane >> 4) << 2) + rr;
          const int n = n0 + wn0 + j * 16 + (lane & 15);
          outH[(size_t)m * HID + n] = f2bf(tanhf(acc0[i][j][rr] + bias[n]));
        }
  } else {  // EPI == 3
#pragma unroll
    for (int i = 0; i < RT; ++i)
#pragma unroll
      for (int rr = 0; rr < 4; ++rr) {
        const int ml = wm0 + i * 16 + ((lane >> 4) << 2) + rr;
        const int m = m0 + ml;
        float s = 0.f;
#pragma unroll
        for (int j = 0; j < CT; ++j) {
          const int n = n0 + wn0 + j * 16 + (lane & 15);
          const size_t idx = (size_t)m * FEAT + n;
          const float dzv = acc0[i][j][rr] + bias[n];
          if constexpr (DUAL) s += acc1[i][j][rr] * bf2f(epsb[idx]);
          if (!finish) {
            zsb[idx] = f2bf(z0[idx] + czs * dzv);
          } else {
            const float v = z0[idx] + dt6 * dzv;
            z0[idx] = v;
            zsb[idx] = f2bf(v);
            if (finZ) finZ[idx] = v;
          }
        }
        if constexpr (DUAL) {
          s += __shfl_xor(s, 8);
          s += __shfl_xor(s, 4);
          s += __shfl_xor(s, 2);
          s += __shfl_xor(s, 1);
          if ((lane & 15) == 0) atomicAdd(&rsum[ml], s);
        }
      }
    if constexpr (DUAL) {
      __syncthreads();
      if (tid < BM && finish) {
        const int m = m0 + tid;
        const float lv = ld0[m] + dt6 * (-rsum[tid]);
        ld0[m] = lv;
        if (finLd) finLd[m] = lv;
      }
    }
  }
}

// Fused prologue: 3 LDS-tiled weight transposes (fp32 -> bf16, N x R layout)
// + eps/z0/zsb/ld0 init. Blocks [0,320) do transpose tiles, rest do prep.
__global__ __launch_bounds__(256) void prologue_k(
    const float* __restrict__ W1, const float* __restrict__ W2,
    const float* __restrict__ W3,
    unsigned short* __restrict__ Wb1t, unsigned short* __restrict__ Wb2t,
    unsigned short* __restrict__ Wb3t,
    const float* __restrict__ x, const float* __restrict__ eps,
    float* __restrict__ z0, unsigned short* __restrict__ zs,
    unsigned short* __restrict__ epsb, float* __restrict__ ld0)
{
  __shared__ unsigned short t[64][65];
  const int b = blockIdx.x;
  if (b < 320) {
    const float* src; unsigned short* dst; int R, N, lb;
    if (b < 32)       { src = W1; dst = Wb1t; R = FEAT; N = HID;  lb = b; }
    else if (b < 288) { src = W2; dst = Wb2t; R = HID;  N = HID;  lb = b - 32; }
    else              { src = W3; dst = Wb3t; R = HID;  N = FEAT; lb = b - 288; }
    const int nt = N >> 6;
    const int bx = lb % nt, by = lb / nt;
    const int r0 = by << 6, c0 = bx << 6;
    const int tx = threadIdx.x & 63, ty = threadIdx.x >> 6;
#pragma unroll
    for (int k = 0; k < 16; ++k) {
      const int rr = ty * 16 + k;
      t[rr][tx] = f2bf(src[(size_t)(r0 + rr) * N + c0 + tx]);
    }
    __syncthreads();
#pragma unroll
    for (int k = 0; k < 16; ++k) {
      const int rr = ty * 16 + k;
      dst[(size_t)(c0 + rr) * R + r0 + tx] = t[tx][rr];
    }
  } else {
    const int i = (b - 320) * 256 + threadIdx.x;
    if (i < BATCH * FEAT) {
      const float v = x[i];
      z0[i] = v; zs[i] = f2bf(v);
      epsb[i] = f2bf(eps[i]);
    }
    if (i < BATCH) ld0[i] = 0.f;
  }
}

extern "C" void kernel_launch(void* const* d_in, const int* in_sizes, int n_in,
                              void* d_out, int out_size, void* d_ws, size_t ws_size,
                              hipStream_t stream) {
  const float* x   = (const float*)d_in[0];
  const float* eps = (const float*)d_in[1];
  const float* W1  = (const float*)d_in[2];   // (129, 1024)
  const float* b1  = (const float*)d_in[3];
  const float* W2  = (const float*)d_in[4];   // (1024, 1024)
  const float* b2  = (const float*)d_in[5];
  const float* W3  = (const float*)d_in[6];   // (1024, 128)
  const float* b3  = (const float*)d_in[7];
  (void)in_sizes; (void)n_in; (void)out_size; (void)ws_size;

  char* p = (char*)d_ws;
  auto alloc = [&](size_t bytes) -> void* {
    void* q = (void*)p;
    p += (bytes + 255) & ~(size_t)255;
    return q;
  };
  unsigned short* Wb1t = (unsigned short*)alloc((size_t)HID * FEAT * 2);   // [1024][128]
  unsigned short* Wb2t = (unsigned short*)alloc((size_t)HID * HID * 2);    // [1024][1024]
  unsigned short* Wb3t = (unsigned short*)alloc((size_t)FEAT * HID * 2);   // [128][1024]
  unsigned short* epsb = (unsigned short*)alloc((size_t)BATCH * FEAT * 2);
  unsigned short* zsb  = (unsigned short*)alloc((size_t)BATCH * FEAT * 2);
  float* z0  = (float*)alloc((size_t)BATCH * FEAT * 4);
  float* ld0 = (float*)alloc((size_t)BATCH * 4);
  unsigned short* h1d = (unsigned short*)alloc((size_t)2 * BATCH * HID * 2);
  unsigned short* h2d = (unsigned short*)alloc((size_t)2 * BATCH * HID * 2);

  const int GB = (BATCH * FEAT + 255) / 256;
  prologue_k<<<dim3(320 + GB), dim3(256), 0, stream>>>(
      W1, W2, W3, Wb1t, Wb2t, Wb3t, x, eps, z0, zsb, epsb, ld0);

  const float dt = 1.f;
  const float* w1l = W1 + (size_t)FEAT * HID;

  // ---- Midpoint RK2, single step over [0,1] ----
  // eval 1 (k1, t=0): PRIMAL ONLY.
  gk<128, 128, 128, 8, 0, 8, 4><<<dim3(1024), dim3(256), 0, stream>>>(
      zsb, nullptr, Wb1t, FEAT, b1, nullptr, 0.f, nullptr,
      h1d, nullptr, nullptr, nullptr, 0.f, 0.f, 0, nullptr, nullptr);
  // G2k1: 128^2 single-stream, K=1024 (counted-vmcnt pipeline).
  gk<128, 128, 128, 8, 0, 8, 4><<<dim3(1024), dim3(256), 0, stream>>>(
      h1d, nullptr, Wb2t, HID, b2, nullptr, 0.f, nullptr,
      h2d, nullptr, nullptr, nullptr, 0.f, 0.f, 0, nullptr, nullptr);
  // G3k1: dz = h2@W3+b3; zsb = bf16(z0 + dt/2*dz). (legacy path, NCH=6)
  gk<32, 64, 512, 2, 0, 3, 4><<<dim3(1024), dim3(256), 0, stream>>>(
      h2d, nullptr, Wb3t, HID, b3, nullptr, 0.f, nullptr,
      nullptr, z0, zsb, nullptr, 0.5f * dt, 0.f, 0, nullptr, nullptr);

  // eval 2 (k2, t=1/2): full primal+tangent, finish
  // G1: dual — h1 = tanh(zs@W1 + t*w1last + b1); dh1 = (1-h1^2)*(eps@W1)
  gk<64, 128, 256, 8, 1, 2, 4><<<dim3(2048), dim3(256), 0, stream>>>(
      zsb, epsb, Wb1t, FEAT, b1, w1l, 0.5f * dt, nullptr,
      h1d, nullptr, nullptr, nullptr, 0.f, 0.f, 0, nullptr, nullptr);
  // G2k2: dual 64x128, K=1024 (counted-vmcnt pipeline).
  gk<64, 128, 256, 8, 1, 2, 4><<<dim3(2048), dim3(256), 0, stream>>>(
      h1d, h1d + (size_t)BATCH * HID, Wb2t, HID, b2, nullptr, 0.f, nullptr,
      h2d, nullptr, nullptr, nullptr, 0.f, 0.f, 0, nullptr, nullptr);
  // G3: dual + finish — z1 = z0 + dt*dz; ld1 = dt*(-trace)
  gk<32, 128, 512, 1, 1, 3><<<dim3(512), dim3(256), 0, stream>>>(
      h2d, h2d + (size_t)BATCH * HID, Wb3t, HID, b3, nullptr, 0.f, epsb,
      nullptr, z0, zsb, ld0, 0.f, dt, 1,
      (float*)d_out, (float*)d_out + (size_t)BATCH * FEAT);
}